// Round 6
// baseline (472.976 us; speedup 1.0000x reference)
//
#include <hip/hip_runtime.h>
#include <cstdint>
#include <cstddef>

// ---- problem constants ----
#define SEQ   2048
#define BATCH 2
#define NH    8
#define NKV   2
#define DH    256
#define HID   2048
#define MR    (BATCH*SEQ)   // 4096

typedef _Float16 h8 __attribute__((ext_vector_type(8)));
typedef _Float16 h4 __attribute__((ext_vector_type(4)));
typedef float   f32x4 __attribute__((ext_vector_type(4)));
typedef int     i32x4 __attribute__((ext_vector_type(4)));

__device__ __forceinline__ f32x4 mfma16(h8 a, h8 b, f32x4 c) {
  return __builtin_amdgcn_mfma_f32_16x16x32_f16(a, b, c, 0, 0, 0);
}
// async global->LDS, 16B/lane. LDS dest = wave-uniform base + lane*16 (linear);
// swizzle is applied on the GLOBAL source address instead.
__device__ __forceinline__ void gload16(const void* g, void* l) {
  __builtin_amdgcn_global_load_lds((__attribute__((address_space(1))) void*)g,
                                   (__attribute__((address_space(3))) void*)l,
                                   16, 0, 0);
}
__device__ __forceinline__ int pkf16(float a, float b) {   // {lo=a, hi=b} f16
  auto t = __builtin_amdgcn_cvt_pkrtz(a, b);   // __fp16 ext_vector(2)
  return __builtin_bit_cast(int, t);
}

// =====================================================================
// fp32 -> fp16 elementwise (hidden states), 4 elems/thread
// =====================================================================
__global__ __launch_bounds__(256) void cvt_f16(const float* __restrict__ in,
                                               _Float16* __restrict__ out, int n4) {
  const int i = blockIdx.x * 256 + threadIdx.x;
  if (i >= n4) return;
  const float4 v = ((const float4*)in)[i];
  h4 o = { (_Float16)v.x, (_Float16)v.y, (_Float16)v.z, (_Float16)v.w };
  ((h4*)out)[i] = o;
}

// =====================================================================
// Weight transpose + cvt: in [K][N] f32 -> out [N][K] f16. 32x32 tiles.
// =====================================================================
__global__ __launch_bounds__(256) void wtrans(const float* __restrict__ in,
                                              _Float16* __restrict__ out,
                                              int N, int K) {
  __shared__ float L[32][33];
  const int n0 = blockIdx.x * 32, k0 = blockIdx.y * 32;
  const int t = threadIdx.x;
  const int r = t >> 3, c4 = (t & 7) * 4;
  const float4 v = *(const float4*)&in[(size_t)(k0 + r) * N + n0 + c4];
  L[r][c4] = v.x; L[r][c4 + 1] = v.y; L[r][c4 + 2] = v.z; L[r][c4 + 3] = v.w;
  __syncthreads();
  h4 o = { (_Float16)L[c4][r], (_Float16)L[c4 + 1][r],
           (_Float16)L[c4 + 2][r], (_Float16)L[c4 + 3][r] };
  *(h4*)&out[(size_t)(n0 + r) * K + k0 + c4] = o;
}

// =====================================================================
// f16 MFMA GEMM: C[M,N] f32 = A[M,K] f16 @ Bt[N,K] f16 (B pre-transposed).
// 128x128 tile, 4 waves (each 64x64), BK=64, 16x16x32 MFMA.
// =====================================================================
__global__ __launch_bounds__(256) void gemm_f16(const _Float16* __restrict__ A,
                                                const _Float16* __restrict__ Bt,
                                                float* __restrict__ C,
                                                const int N, const int K) {
  __shared__ __align__(16) unsigned char sm[32768];   // A [0,16K), B [16K,32K)
  const int t = threadIdx.x, w = t >> 6, lane = t & 63;
  const int l15 = lane & 15, l4 = lane >> 4;
  const int wr = w >> 1, wc = w & 1;
  const int m0 = blockIdx.y * 128, n0 = blockIdx.x * 128;
  const int swz = (l15 & 7) << 4;
  const size_t rb = (size_t)K * 2;           // row bytes

  int rS[4], cS[4];                          // staging geometry (A and B identical)
#pragma unroll
  for (int i = 0; i < 4; ++i) {
    const int o = i * 4096 + w * 1024 + lane * 16;
    rS[i] = o >> 7;
    cS[i] = (o & 127) ^ ((rS[i] & 7) << 4);
  }
  const char* Ab = (const char*)A + (size_t)m0 * rb;
  const char* Bb = (const char*)Bt + (size_t)n0 * rb;

  f32x4 acc[4][4] = {};

  for (int k0 = 0; k0 < K; k0 += 64) {
    __syncthreads();
#pragma unroll
    for (int i = 0; i < 4; ++i) {
      gload16(Ab + (size_t)rS[i] * rb + k0 * 2 + cS[i], sm + i * 4096 + w * 1024);
      gload16(Bb + (size_t)rS[i] * rb + k0 * 2 + cS[i], sm + 16384 + i * 4096 + w * 1024);
    }
    __syncthreads();
#pragma unroll
    for (int kk = 0; kk < 2; ++kk) {
      const int ko = (kk * 64 + l4 * 16) ^ swz;
      h8 av[4], bv[4];
#pragma unroll
      for (int f = 0; f < 4; ++f) {
        av[f] = *(const h8*)(sm + (wr * 64 + f * 16 + l15) * 128 + ko);
        bv[f] = *(const h8*)(sm + 16384 + (wc * 64 + f * 16 + l15) * 128 + ko);
      }
#pragma unroll
      for (int i = 0; i < 4; ++i)
#pragma unroll
        for (int j = 0; j < 4; ++j)
          acc[i][j] = mfma16(av[i], bv[j], acc[i][j]);
    }
  }
  // C/D layout: col = lane&15, row = (lane>>4)*4 + reg
#pragma unroll
  for (int i = 0; i < 4; ++i)
#pragma unroll
    for (int r = 0; r < 4; ++r) {
      const int row = m0 + wr * 64 + i * 16 + l4 * 4 + r;
      float* Cp = C + (size_t)row * N + n0 + wc * 64 + l15;
#pragma unroll
      for (int j = 0; j < 4; ++j) Cp[j * 16] = acc[i][j][r];
    }
}

// =====================================================================
// RMSNorm(+q_scale)+RoPE for Q rows of fused QKVp [4096][3072].
// Also folds the softmax 1/sqrt(256) into Q. Out: Qh f16 [b][h][s][256].
// =====================================================================
__global__ __launch_bounds__(256) void norm_rope_q(const float* __restrict__ QKVp,
                                                   _Float16* __restrict__ Qh,
                                                   const float* __restrict__ q_scale) {
  const int idx = blockIdx.x;           // ((b*2048+s)*8 + h)
  const int t = threadIdx.x;
  const int h = idx & 7;
  const int bs = idx >> 3;
  const int s = bs & (SEQ - 1);
  const int b = bs >> 11;
  const float x = QKVp[(size_t)bs * 3072 + h * 256 + t];
  float ss = x * x;
#pragma unroll
  for (int off = 32; off; off >>= 1) ss += __shfl_xor(ss, off);
  __shared__ float red[4];
  if ((t & 63) == 0) red[t >> 6] = ss;
  __syncthreads();
  const float tot = red[0] + red[1] + red[2] + red[3];
  const float inv = rsqrtf(tot * (1.0f / 256.0f) + 1e-6f);
  const float xn = x * inv * q_scale[t];
  __shared__ float rowbuf[256];
  rowbuf[t] = xn;
  __syncthreads();
  const int f = t & 127;
  const float invf = expf(-0.07195578415606391f * (float)f);   // 10000^(-f/128)
  float sn, cs;
  sincosf((float)s * invf, &sn, &cs);
  const float other = rowbuf[t ^ 128];
  const float o = (t < 128) ? (xn * cs - other * sn) : (xn * cs + other * sn);
  Qh[((size_t)(b * NH + h) * SEQ + s) * DH + t] = (_Float16)(o * 0.0625f);
}

// =====================================================================
// RMSNorm(+rope,k_scale) for K rows, RMSNorm-only for V rows of QKVp.
// =====================================================================
__global__ __launch_bounds__(256) void norm_kv(const float* __restrict__ QKVp,
                                               _Float16* __restrict__ Kh,
                                               _Float16* __restrict__ Vh,
                                               const float* __restrict__ k_scale) {
  const int idx = blockIdx.x;
  const int t = threadIdx.x;
  const bool isK = idx < 8192;
  const int i = isK ? idx : idx - 8192;   // ((b*2048+s)*2 + kv)
  const int kv = i & 1;
  const int bs = i >> 1;
  const int s = bs & (SEQ - 1);
  const int b = bs >> 11;
  const int col = (isK ? 2048 + kv * DH : 2560 + kv * DH) + t;
  const float x = QKVp[(size_t)bs * 3072 + col];
  float ss = x * x;
#pragma unroll
  for (int off = 32; off; off >>= 1) ss += __shfl_xor(ss, off);
  __shared__ float red[4];
  if ((t & 63) == 0) red[t >> 6] = ss;
  __syncthreads();
  const float tot = red[0] + red[1] + red[2] + red[3];
  const float inv = rsqrtf(tot * (1.0f / 256.0f) + 1e-6f);
  float xn = x * inv;
  const size_t o = ((size_t)(b * NKV + kv) * SEQ + s) * DH + t;
  if (isK) {
    xn *= k_scale[t];
    __shared__ float rowbuf[256];
    rowbuf[t] = xn;
    __syncthreads();
    const int f = t & 127;
    const float invf = expf(-0.07195578415606391f * (float)f);
    float sn, cs;
    sincosf((float)s * invf, &sn, &cs);
    const float other = rowbuf[t ^ 128];
    const float ov = (t < 128) ? (xn * cs - other * sn) : (xn * cs + other * sn);
    Kh[o] = (_Float16)ov;
  } else {
    Vh[o] = (_Float16)xn;
  }
}

// =====================================================================
// V transpose: per (b,kv): [2048 s][256 d] -> Vt [256 d][2048 s]. 32x32 tiles.
// =====================================================================
__global__ __launch_bounds__(256) void transpose_v(const _Float16* __restrict__ Vh,
                                                   _Float16* __restrict__ Vt) {
  __shared__ _Float16 L[32][36];
  const int s0 = blockIdx.x * 32, d0 = blockIdx.y * 32;
  const size_t base = (size_t)blockIdx.z * SEQ * DH;
  const int t = threadIdx.x;
  const int r = t >> 3, c4 = (t & 7) * 4;
  const h4 v = *(const h4*)&Vh[base + (size_t)(s0 + r) * DH + d0 + c4];
  L[r][c4] = v.x; L[r][c4 + 1] = v.y; L[r][c4 + 2] = v.z; L[r][c4 + 3] = v.w;
  __syncthreads();
  h4 o = { L[c4][r], L[c4 + 1][r], L[c4 + 2][r], L[c4 + 3][r] };
  *(h4*)&Vt[base + (size_t)(d0 + r) * SEQ + s0 + c4] = o;
}

// =====================================================================
// Flash attention v3, f16 MFMA, causal, GQA (head h -> kv head h>>2).
// Block: 256 thr, 4 waves x 32 q-rows = BQ 128. Grid (16,8,2) = 256 = 1/CU.
// KV tile = 32 rows, DOUBLE-BUFFERED (2 x (K 16KB + V 16KB) = 64KB LDS).
// Pipeline: issue stage(kt+1 -> buf^1) BEFORE compute(kt); single
// __syncthreads per tile (its vmcnt0 drain lands after a tile of overlap).
// Wave w handles q rows [q0+w*32, +32) as two 16-row fragment groups g.
// Each K/V LDS read feeds both g-groups (halves LDS traffic vs R5).
// Q loaded direct global->regs. Swapped QK^T; in-register softmax + P.
// K LDS rows 512B swizzle ((row&7)<<4); V LDS rows 64B swizzle ((row&3)<<4).
// =====================================================================
__global__ __launch_bounds__(256, 1) void attn_f16(const _Float16* __restrict__ Qh,
                                                   const _Float16* __restrict__ Kh,
                                                   const _Float16* __restrict__ Vt,
                                                   _Float16* __restrict__ Ah) {
  __shared__ __align__(16) unsigned char sm[65536];  // buf p: K @ p*32768, V @ +16384
  const int qt = blockIdx.x;           // 0..15
  const int h = blockIdx.y, b = blockIdx.z;
  const int kh = h >> 2;
  const int q0 = qt * 128;
  const int nt = 4 * (qt + 1);
  const int t = threadIdx.x, w = t >> 6, lane = t & 63;
  const int l15 = lane & 15, l4 = lane >> 4;
  const int swzk = (l15 & 7) << 4;     // K read swizzle (512B rows)
  const int swzv = (l15 & 3) << 4;     // V read swizzle (64B rows)

  const char* Qg = (const char*)(Qh + (size_t)(b * NH + h) * SEQ * DH);
  const char* Kg = (const char*)(Kh + (size_t)(b * NKV + kh) * SEQ * DH);
  const char* Vg = (const char*)(Vt + (size_t)(b * NKV + kh) * DH * SEQ);

  auto stage_tile = [&](int kt, int p) {
    unsigned char* Kb = sm + p * 32768;
    unsigned char* Vb = Kb + 16384;
#pragma unroll
    for (int i = 0; i < 4; ++i) {
      const int o = i * 4096 + w * 1024 + lane * 16;
      const int row = o >> 9;                       // 0..31
      const int koff = (o & 511) ^ ((row & 7) << 4);
      gload16(Kg + (size_t)(kt * 32 + row) * 512 + koff, Kb + i * 4096 + w * 1024);
      const int d = o >> 6;                         // 0..255
      const int voff = (o & 63) ^ ((d & 3) << 4);
      gload16(Vg + (size_t)d * (SEQ * 2) + kt * 64 + voff, Vb + i * 4096 + w * 1024);
    }
  };

  stage_tile(0, 0);

  // ---- Q direct to registers: qf[g][dc] = Q[q0+w*32+g*16+l15][dc window] ----
  h8 qf[2][8];
#pragma unroll
  for (int g = 0; g < 2; ++g) {
    const int qrow = q0 + w * 32 + g * 16 + l15;
#pragma unroll
    for (int dc = 0; dc < 8; ++dc)
      qf[g][dc] = *(const h8*)(Qg + (size_t)qrow * 512 + dc * 64 + l4 * 16);
  }

  f32x4 o_acc[2][16] = {};
  float mrun[2] = { -3e38f, -3e38f };
  float lrun[2] = { 0.f, 0.f };
  __syncthreads();                       // tile 0 staged (drain + barrier)

  for (int kt = 0; kt < nt; ++kt) {
    const int p = kt & 1;
    if (kt + 1 < nt) stage_tile(kt + 1, p ^ 1);    // async; lands by next barrier

    if (kt * 32 <= q0 + w * 32 + 31) {             // wave-uniform skip
      const unsigned char* Kb = sm + p * 32768;
      const unsigned char* Vb = Kb + 16384;

      // ---- QK^T (swapped): P[k = kt*32+fk*16+l4*4+r][q = ...+l15] ----
      f32x4 sc[2][2];
#pragma unroll
      for (int fk = 0; fk < 2; ++fk) {
        f32x4 a0 = {}, a1 = {};
        const int krow = fk * 16 + l15;
#pragma unroll
        for (int dc = 0; dc < 8; ++dc) {
          const h8 kf = *(const h8*)(Kb + krow * 512 + ((dc * 64 + l4 * 16) ^ swzk));
          a0 = mfma16(kf, qf[0][dc], a0);
          a1 = mfma16(kf, qf[1][dc], a1);
        }
        sc[0][fk] = a0; sc[1][fk] = a1;
      }

      // ---- per-g softmax + P->A-fragment build (all in-register) ----
      h8 pa[2];
#pragma unroll
      for (int g = 0; g < 2; ++g) {
        const int qlo = q0 + w * 32 + g * 16;
        const int qrow = qlo + l15;
        float e[2][4];
        if (kt * 32 + 31 > qlo) {                  // diagonal band: mask
#pragma unroll
          for (int fk = 0; fk < 2; ++fk)
#pragma unroll
            for (int r = 0; r < 4; ++r)
              e[fk][r] = (kt * 32 + fk * 16 + l4 * 4 + r <= qrow) ? sc[g][fk][r]
                                                                  : -3e38f;
        } else {
#pragma unroll
          for (int fk = 0; fk < 2; ++fk)
#pragma unroll
            for (int r = 0; r < 4; ++r) e[fk][r] = sc[g][fk][r];
        }
        float pm = -3e38f;
#pragma unroll
        for (int fk = 0; fk < 2; ++fk)
#pragma unroll
          for (int r = 0; r < 4; ++r) pm = fmaxf(pm, e[fk][r]);
        pm = fmaxf(pm, __shfl_xor(pm, 16));
        pm = fmaxf(pm, __shfl_xor(pm, 32));
        const float mnew = fmaxf(mrun[g], pm);
        const float alpha = __expf(mrun[g] - mnew);
        mrun[g] = mnew;
        float ls = 0.f;
#pragma unroll
        for (int fk = 0; fk < 2; ++fk)
#pragma unroll
          for (int r = 0; r < 4; ++r) {
            e[fk][r] = __expf(e[fk][r] - mnew);
            ls += e[fk][r];
          }
        ls += __shfl_xor(ls, 16);
        ls += __shfl_xor(ls, 32);
        lrun[g] = lrun[g] * alpha + ls;

        float al[4];
#pragma unroll
        for (int r = 0; r < 4; ++r) al[r] = __shfl(alpha, l4 * 4 + r);
#pragma unroll
        for (int fd = 0; fd < 16; ++fd)
#pragma unroll
          for (int r = 0; r < 4; ++r) o_acc[g][fd][r] *= al[r];

        // pack + redistribute: target lane holds P[q=l15][k = l4*8..+8]
        const int d0 = pkf16(e[0][0], e[0][1]);
        const int d1 = pkf16(e[0][2], e[0][3]);
        const int d2 = pkf16(e[1][0], e[1][1]);
        const int d3 = pkf16(e[1][2], e[1][3]);
        const int src0 = l15 + ((l4 & 1) << 5);
        const int src1 = src0 + 16;
        const bool lowk = (l4 < 2);
        const int s00 = __shfl(d0, src0);
        const int s10 = __shfl(d1, src0);
        const int s20 = __shfl(d2, src0);
        const int s30 = __shfl(d3, src0);
        const int s01 = __shfl(d0, src1);
        const int s11 = __shfl(d1, src1);
        const int s21 = __shfl(d2, src1);
        const int s31 = __shfl(d3, src1);
        i32x4 pw = { lowk ? s00 : s20, lowk ? s10 : s30,
                     lowk ? s01 : s21, lowk ? s11 : s31 };
        pa[g] = __builtin_bit_cast(h8, pw);
      }

      // ---- PV: each V read feeds both g ----
      const int ko = (l4 * 16) ^ swzv;
#pragma unroll
      for (int fd = 0; fd < 16; ++fd) {
        const h8 vf = *(const h8*)(Vb + (fd * 16 + l15) * 64 + ko);
        o_acc[0][fd] = mfma16(pa[0], vf, o_acc[0][fd]);
        o_acc[1][fd] = mfma16(pa[1], vf, o_acc[1][fd]);
      }
    }
    __syncthreads();   // all waves done with buf[p]; stage(kt+1) fully landed
  }

  // ---- epilogue: /l, store f16 to [b][s][h*256] ----
#pragma unroll
  for (int g = 0; g < 2; ++g) {
    const float inv = 1.0f / lrun[g];
#pragma unroll
    for (int r = 0; r < 4; ++r) {
      const float linv = __shfl(inv, l4 * 4 + r);
      const int srow = q0 + w * 32 + g * 16 + l4 * 4 + r;
      _Float16* Op = Ah + (size_t)(b * SEQ + srow) * (NH * DH) + h * DH + l15;
#pragma unroll
      for (int fd = 0; fd < 16; ++fd)
        Op[fd * 16] = (_Float16)(o_acc[g][fd][r] * linv);
    }
  }
}

// =====================================================================
// Launch. d_in: hidden, mask(unused), wq, wk, wv, wo, q_scale, k_scale.
// =====================================================================
extern "C" void kernel_launch(void* const* d_in, const int* in_sizes, int n_in,
                              void* d_out, int out_size, void* d_ws, size_t ws_size,
                              hipStream_t stream) {
  (void)in_sizes; (void)n_in; (void)out_size; (void)ws_size;
  const float* hidden  = (const float*)d_in[0];
  const float* wq      = (const float*)d_in[2];
  const float* wk      = (const float*)d_in[3];
  const float* wv      = (const float*)d_in[4];
  const float* wo      = (const float*)d_in[5];
  const float* q_scale = (const float*)d_in[6];
  const float* k_scale = (const float*)d_in[7];
  float* out = (float*)d_out;

  uint8_t* ws = (uint8_t*)d_ws;
  _Float16* hid_h = (_Float16*)ws;  ws += (size_t)MR * HID * 2;        // 16.78MB
  _Float16* Wt    = (_Float16*)ws;  ws += (size_t)3072 * HID * 2;      // 12.58MB (QKV^T; reused for wo^T)
  float*    QKVp  = (float*)ws;     ws += (size_t)MR * 3072 * 4;       // 50.33MB (reused as Ah)
  _Float16* Qh    = (_Float16*)ws;  ws += (size_t)MR * HID * 2;        // 16.78MB
  _Float16* Kh    = (_Float16*)ws;  ws += (size_t)MR * 512 * 2;        // 4.19MB
  _Float16* Vh    = (_Float16*)ws;  ws += (size_t)MR * 512 * 2;        // 4.19MB
  _Float16* Vt    = (_Float16*)ws;  ws += (size_t)MR * 512 * 2;        // 4.19MB
  _Float16* Ah    = (_Float16*)QKVp;  // overlay (QKVp dead after norms)

  const dim3 blk(256);
  cvt_f16<<<dim3(8192), blk, 0, stream>>>(hidden, hid_h, MR * HID / 4);
  wtrans<<<dim3(64, 64), blk, 0, stream>>>(wq, Wt, 2048, 2048);
  wtrans<<<dim3(16, 64), blk, 0, stream>>>(wk, Wt + (size_t)2048 * 2048, 512, 2048);
  wtrans<<<dim3(16, 64), blk, 0, stream>>>(wv, Wt + (size_t)2560 * 2048, 512, 2048);
  // fused QKV projection: [4096,2048] @ [2048,3072]
  gemm_f16<<<dim3(24, 32), blk, 0, stream>>>(hid_h, Wt, QKVp, 3072, 2048);
  // Wt is free now -> wo^T
  wtrans<<<dim3(64, 64), blk, 0, stream>>>(wo, Wt, 2048, 2048);
  norm_rope_q<<<dim3(32768), blk, 0, stream>>>(QKVp, Qh, q_scale);
  norm_kv<<<dim3(16384), blk, 0, stream>>>(QKVp, Kh, Vh, k_scale);
  transpose_v<<<dim3(64, 8, 4), blk, 0, stream>>>(Vh, Vt);
  attn_f16<<<dim3(16, 8, 2), blk, 0, stream>>>(Qh, Kh, Vt, Ah);
  gemm_f16<<<dim3(16, 32), blk, 0, stream>>>(Ah, Wt, out, 2048, 2048);
}

// Round 10
// 450.646 us; speedup vs baseline: 1.0496x; 1.0496x over previous
//
#include <hip/hip_runtime.h>
#include <cstdint>
#include <cstddef>

// ---- problem constants ----
#define SEQ   2048
#define BATCH 2
#define NH    8
#define NKV   2
#define DH    256
#define HID   2048
#define MR    (BATCH*SEQ)   // 4096

typedef _Float16 h8 __attribute__((ext_vector_type(8)));
typedef _Float16 h4 __attribute__((ext_vector_type(4)));
typedef float   f32x4 __attribute__((ext_vector_type(4)));
typedef int     i32x4 __attribute__((ext_vector_type(4)));

__device__ __forceinline__ f32x4 mfma16(h8 a, h8 b, f32x4 c) {
  return __builtin_amdgcn_mfma_f32_16x16x32_f16(a, b, c, 0, 0, 0);
}
// async global->LDS, 16B/lane. LDS dest = wave-uniform base + lane*16 (linear);
// swizzle is applied on the GLOBAL source address instead.
__device__ __forceinline__ void gload16(const void* g, void* l) {
  __builtin_amdgcn_global_load_lds((__attribute__((address_space(1))) void*)g,
                                   (__attribute__((address_space(3))) void*)l,
                                   16, 0, 0);
}
__device__ __forceinline__ int pkf16(float a, float b) {   // {lo=a, hi=b} f16
  auto t = __builtin_amdgcn_cvt_pkrtz(a, b);
  return __builtin_bit_cast(int, t);
}

// =====================================================================
// fp32 -> fp16 elementwise (hidden states), 4 elems/thread
// =====================================================================
__global__ __launch_bounds__(256) void cvt_f16(const float* __restrict__ in,
                                               _Float16* __restrict__ out, int n4) {
  const int i = blockIdx.x * 256 + threadIdx.x;
  if (i >= n4) return;
  const float4 v = ((const float4*)in)[i];
  h4 o = { (_Float16)v.x, (_Float16)v.y, (_Float16)v.z, (_Float16)v.w };
  ((h4*)out)[i] = o;
}

// =====================================================================
// Weight transpose + cvt: in [K][N] f32 -> out [N][K] f16. 32x32 tiles.
// =====================================================================
__global__ __launch_bounds__(256) void wtrans(const float* __restrict__ in,
                                              _Float16* __restrict__ out,
                                              int N, int K) {
  __shared__ float L[32][33];
  const int n0 = blockIdx.x * 32, k0 = blockIdx.y * 32;
  const int t = threadIdx.x;
  const int r = t >> 3, c4 = (t & 7) * 4;
  const float4 v = *(const float4*)&in[(size_t)(k0 + r) * N + n0 + c4];
  L[r][c4] = v.x; L[r][c4 + 1] = v.y; L[r][c4 + 2] = v.z; L[r][c4 + 3] = v.w;
  __syncthreads();
  h4 o = { (_Float16)L[c4][r], (_Float16)L[c4 + 1][r],
           (_Float16)L[c4 + 2][r], (_Float16)L[c4 + 3][r] };
  *(h4*)&out[(size_t)(n0 + r) * K + k0 + c4] = o;
}

// =====================================================================
// f16 MFMA GEMM: C[M,N] f32 = A[M,K] f16 @ Bt[N,K] f16 (B pre-transposed).
// 128x128 tile, 4 waves (each 64x64), BK=64, 16x16x32 MFMA.
// =====================================================================
__global__ __launch_bounds__(256) void gemm_f16(const _Float16* __restrict__ A,
                                                const _Float16* __restrict__ Bt,
                                                float* __restrict__ C,
                                                const int N, const int K) {
  __shared__ __align__(16) unsigned char sm[32768];   // A [0,16K), B [16K,32K)
  const int t = threadIdx.x, w = t >> 6, lane = t & 63;
  const int l15 = lane & 15, l4 = lane >> 4;
  const int wr = w >> 1, wc = w & 1;
  const int m0 = blockIdx.y * 128, n0 = blockIdx.x * 128;
  const int swz = (l15 & 7) << 4;
  const size_t rb = (size_t)K * 2;           // row bytes

  int rS[4], cS[4];                          // staging geometry (A and B identical)
#pragma unroll
  for (int i = 0; i < 4; ++i) {
    const int o = i * 4096 + w * 1024 + lane * 16;
    rS[i] = o >> 7;
    cS[i] = (o & 127) ^ ((rS[i] & 7) << 4);
  }
  const char* Ab = (const char*)A + (size_t)m0 * rb;
  const char* Bb = (const char*)Bt + (size_t)n0 * rb;

  f32x4 acc[4][4] = {};

  for (int k0 = 0; k0 < K; k0 += 64) {
    __syncthreads();
#pragma unroll
    for (int i = 0; i < 4; ++i) {
      gload16(Ab + (size_t)rS[i] * rb + k0 * 2 + cS[i], sm + i * 4096 + w * 1024);
      gload16(Bb + (size_t)rS[i] * rb + k0 * 2 + cS[i], sm + 16384 + i * 4096 + w * 1024);
    }
    __syncthreads();
#pragma unroll
    for (int kk = 0; kk < 2; ++kk) {
      const int ko = (kk * 64 + l4 * 16) ^ swz;
      h8 av[4], bv[4];
#pragma unroll
      for (int f = 0; f < 4; ++f) {
        av[f] = *(const h8*)(sm + (wr * 64 + f * 16 + l15) * 128 + ko);
        bv[f] = *(const h8*)(sm + 16384 + (wc * 64 + f * 16 + l15) * 128 + ko);
      }
#pragma unroll
      for (int i = 0; i < 4; ++i)
#pragma unroll
        for (int j = 0; j < 4; ++j)
          acc[i][j] = mfma16(av[i], bv[j], acc[i][j]);
    }
  }
  // C/D layout: col = lane&15, row = (lane>>4)*4 + reg
#pragma unroll
  for (int i = 0; i < 4; ++i)
#pragma unroll
    for (int r = 0; r < 4; ++r) {
      const int row = m0 + wr * 64 + i * 16 + l4 * 4 + r;
      float* Cp = C + (size_t)row * N + n0 + wc * 64 + l15;
#pragma unroll
      for (int j = 0; j < 4; ++j) Cp[j * 16] = acc[i][j][r];
    }
}

// =====================================================================
// RoPE cos/sin table: tab[s][f] = {cos(s*invf), sin(s*invf)}, f<128.
// =====================================================================
__global__ __launch_bounds__(128) void rope_tab(float2* __restrict__ tab) {
  const int s = blockIdx.x, f = threadIdx.x;
  const float invf = expf(-0.07195578415606391f * (float)f);   // 10000^(-f/128)
  float sn, cs;
  sincosf((float)s * invf, &sn, &cs);
  tab[(size_t)s * 128 + f] = make_float2(cs, sn);
}

// =====================================================================
// RMSNorm(+q_scale)+RoPE for Q rows of fused QKVp [4096][3072].
// Also folds the softmax 1/sqrt(256) into Q. Out: Qh f16 [b][h][s][256].
// =====================================================================
__global__ __launch_bounds__(256) void norm_rope_q(const float* __restrict__ QKVp,
                                                   _Float16* __restrict__ Qh,
                                                   const float* __restrict__ q_scale,
                                                   const float2* __restrict__ tab) {
  const int idx = blockIdx.x;           // ((b*2048+s)*8 + h)
  const int t = threadIdx.x;
  const int h = idx & 7;
  const int bs = idx >> 3;
  const int s = bs & (SEQ - 1);
  const int b = bs >> 11;
  const float x = QKVp[(size_t)bs * 3072 + h * 256 + t];
  float ss = x * x;
#pragma unroll
  for (int off = 32; off; off >>= 1) ss += __shfl_xor(ss, off);
  __shared__ float red[4];
  if ((t & 63) == 0) red[t >> 6] = ss;
  __syncthreads();
  const float tot = red[0] + red[1] + red[2] + red[3];
  const float inv = rsqrtf(tot * (1.0f / 256.0f) + 1e-6f);
  const float xn = x * inv * q_scale[t];
  __shared__ float rowbuf[256];
  rowbuf[t] = xn;
  __syncthreads();
  const float2 cst = tab[(size_t)s * 128 + (t & 127)];
  const float other = rowbuf[t ^ 128];
  const float o = (t < 128) ? (xn * cst.x - other * cst.y)
                            : (xn * cst.x + other * cst.y);
  Qh[((size_t)(b * NH + h) * SEQ + s) * DH + t] = (_Float16)(o * 0.0625f);
}

// =====================================================================
// RMSNorm(+rope,k_scale) for K rows, RMSNorm-only for V rows of QKVp.
// =====================================================================
__global__ __launch_bounds__(256) void norm_kv(const float* __restrict__ QKVp,
                                               _Float16* __restrict__ Kh,
                                               _Float16* __restrict__ Vh,
                                               const float* __restrict__ k_scale,
                                               const float2* __restrict__ tab) {
  const int idx = blockIdx.x;
  const int t = threadIdx.x;
  const bool isK = idx < 8192;
  const int i = isK ? idx : idx - 8192;   // ((b*2048+s)*2 + kv)
  const int kv = i & 1;
  const int bs = i >> 1;
  const int s = bs & (SEQ - 1);
  const int b = bs >> 11;
  const int col = (isK ? 2048 + kv * DH : 2560 + kv * DH) + t;
  const float x = QKVp[(size_t)bs * 3072 + col];
  float ss = x * x;
#pragma unroll
  for (int off = 32; off; off >>= 1) ss += __shfl_xor(ss, off);
  __shared__ float red[4];
  if ((t & 63) == 0) red[t >> 6] = ss;
  __syncthreads();
  const float tot = red[0] + red[1] + red[2] + red[3];
  const float inv = rsqrtf(tot * (1.0f / 256.0f) + 1e-6f);
  float xn = x * inv;
  const size_t o = ((size_t)(b * NKV + kv) * SEQ + s) * DH + t;
  if (isK) {
    xn *= k_scale[t];
    __shared__ float rowbuf[256];
    rowbuf[t] = xn;
    __syncthreads();
    const float2 cst = tab[(size_t)s * 128 + (t & 127)];
    const float other = rowbuf[t ^ 128];
    const float ov = (t < 128) ? (xn * cst.x - other * cst.y)
                               : (xn * cst.x + other * cst.y);
    Kh[o] = (_Float16)ov;
  } else {
    Vh[o] = (_Float16)xn;
  }
}

// =====================================================================
// V transpose: per (b,kv): [2048 s][256 d] -> Vt [256 d][2048 s]. 32x32 tiles.
// =====================================================================
__global__ __launch_bounds__(256) void transpose_v(const _Float16* __restrict__ Vh,
                                                   _Float16* __restrict__ Vt) {
  __shared__ _Float16 L[32][36];
  const int s0 = blockIdx.x * 32, d0 = blockIdx.y * 32;
  const size_t base = (size_t)blockIdx.z * SEQ * DH;
  const int t = threadIdx.x;
  const int r = t >> 3, c4 = (t & 7) * 4;
  const h4 v = *(const h4*)&Vh[base + (size_t)(s0 + r) * DH + d0 + c4];
  L[r][c4] = v.x; L[r][c4 + 1] = v.y; L[r][c4 + 2] = v.z; L[r][c4 + 3] = v.w;
  __syncthreads();
  h4 o = { L[c4][r], L[c4 + 1][r], L[c4 + 2][r], L[c4 + 3][r] };
  *(h4*)&Vt[base + (size_t)(d0 + r) * SEQ + s0 + c4] = o;
}

// =====================================================================
// Flash attention v5, f16 MFMA, causal, GQA (head h -> kv head h>>2).
// Block: 128 thr (2 waves), wave w owns 32 q-rows (2 groups g of 16).
// Grid (32,8,2) = 512 blocks; qt = b ? 31-pid : pid (R5 pairing: blocks
// with linear-id delta 256 have complementary causal depth).
// KV tile 32 rows, double-buffered (2 x (K16K + V16K) = 64KB -> 2 blk/CU).
// Per tile: stage(kt+1) first, then compute kt; one barrier per tile.
// K/V fragments BATCH-loaded to registers (16 ds_reads in flight, one
// wait) -- R6's 1-wave/SIMD latency exposure fix. defer-max (THR=8)
// skips O-rescale + alpha shfl broadcast on max-stable tiles.
// K LDS swizzle (row&15)<<4 (full 4-bit spread); V rows 64B, (d&3)<<4.
// =====================================================================
__global__ __launch_bounds__(128, 1) void attn_f16(const _Float16* __restrict__ Qh,
                                                   const _Float16* __restrict__ Kh,
                                                   const _Float16* __restrict__ Vt,
                                                   _Float16* __restrict__ Ah) {
  __shared__ __align__(16) unsigned char sm[65536];  // buf p: K @ p*32768, V @ +16384
  const int pid = blockIdx.x;          // 0..31
  const int h = blockIdx.y, b = blockIdx.z;
  const int kh = h >> 2;
  const int qt = b ? (31 - pid) : pid;
  const int q0 = qt * 64;
  const int nt = 2 * (qt + 1);         // 32-row kv tiles
  const int t = threadIdx.x, w = t >> 6, lane = t & 63;
  const int l15 = lane & 15, l4 = lane >> 4;
  const int swzk = l15 << 4;           // K read swizzle (512B rows, row&15 = l15)
  const int swzv = (l15 & 3) << 4;     // V read swizzle (64B rows)

  const char* Qg = (const char*)(Qh + (size_t)(b * NH + h) * SEQ * DH);
  const char* Kg = (const char*)(Kh + (size_t)(b * NKV + kh) * SEQ * DH);
  const char* Vg = (const char*)(Vt + (size_t)(b * NKV + kh) * DH * SEQ);

  auto stage_tile = [&](int kt, int p) {
    unsigned char* Kb = sm + p * 32768;
    unsigned char* Vb = Kb + 16384;
#pragma unroll
    for (int i = 0; i < 8; ++i) {
      const int o = i * 2048 + w * 1024 + lane * 16;     // 0..16K
      const int row = o >> 9;                            // 0..31
      const int koff = (o & 511) ^ ((row & 15) << 4);
      gload16(Kg + (size_t)(kt * 32 + row) * 512 + koff, Kb + i * 2048 + w * 1024);
      const int d = o >> 6;                              // 0..255
      const int voff = (o & 63) ^ ((d & 3) << 4);
      gload16(Vg + (size_t)d * (SEQ * 2) + kt * 64 + voff, Vb + i * 2048 + w * 1024);
    }
  };

  stage_tile(0, 0);

  // ---- Q direct to registers: qf[g][dc] = Q[q0+w*32+g*16+l15] ----
  h8 qf[2][8];
#pragma unroll
  for (int g = 0; g < 2; ++g) {
    const int qrow = q0 + w * 32 + g * 16 + l15;
#pragma unroll
    for (int dc = 0; dc < 8; ++dc)
      qf[g][dc] = *(const h8*)(Qg + (size_t)qrow * 512 + dc * 64 + l4 * 16);
  }

  f32x4 o_acc[2][16] = {};
  float mrun[2] = { -3e38f, -3e38f };
  float lrun[2] = { 0.f, 0.f };
  __syncthreads();                       // tile 0 staged

  for (int kt = 0; kt < nt; ++kt) {
    const int p = kt & 1;
    if (kt + 1 < nt) stage_tile(kt + 1, p ^ 1);      // async; lands by barrier

    if (kt * 32 <= q0 + w * 32 + 31) {               // wave-uniform skip
      const unsigned char* Kb = sm + p * 32768;
      const unsigned char* Vb = Kb + 16384;

      // ---- batch-load all K fragments, then QK^T (swapped) ----
      h8 kf[2][8];
#pragma unroll
      for (int fk = 0; fk < 2; ++fk)
#pragma unroll
        for (int dc = 0; dc < 8; ++dc)
          kf[fk][dc] = *(const h8*)(Kb + (fk * 16 + l15) * 512 +
                                    ((dc * 64 + l4 * 16) ^ swzk));
      f32x4 sc[2][2] = {};
      __builtin_amdgcn_s_setprio(1);
#pragma unroll
      for (int fk = 0; fk < 2; ++fk)
#pragma unroll
        for (int dc = 0; dc < 8; ++dc) {
          sc[0][fk] = mfma16(kf[fk][dc], qf[0][dc], sc[0][fk]);
          sc[1][fk] = mfma16(kf[fk][dc], qf[1][dc], sc[1][fk]);
        }
      __builtin_amdgcn_s_setprio(0);

      // ---- batch-load V fragments (overlaps softmax below) ----
      h8 vf[16];
#pragma unroll
      for (int fd = 0; fd < 16; ++fd)
        vf[fd] = *(const h8*)(Vb + (fd * 16 + l15) * 64 + ((l4 * 16) ^ swzv));

      // ---- per-g softmax + P->A-fragment (in-register, defer-max) ----
      // lane holds P[k = kt*32+fk*16+l4*4+r][q = q0+w*32+g*16+l15]
      h8 pa[2];
#pragma unroll
      for (int g = 0; g < 2; ++g) {
        const int qlo = q0 + w * 32 + g * 16;
        float e[2][4];
        if (kt * 32 + 31 > qlo) {                    // diagonal band: mask
#pragma unroll
          for (int fk = 0; fk < 2; ++fk)
#pragma unroll
            for (int r = 0; r < 4; ++r)
              e[fk][r] = (kt * 32 + fk * 16 + l4 * 4 + r <= qlo + l15)
                             ? sc[g][fk][r] : -3e38f;
        } else {
#pragma unroll
          for (int fk = 0; fk < 2; ++fk)
#pragma unroll
            for (int r = 0; r < 4; ++r) e[fk][r] = sc[g][fk][r];
        }
        float pm = -3e38f;
#pragma unroll
        for (int fk = 0; fk < 2; ++fk)
#pragma unroll
          for (int r = 0; r < 4; ++r) pm = fmaxf(pm, e[fk][r]);
        pm = fmaxf(pm, __shfl_xor(pm, 16));
        pm = fmaxf(pm, __shfl_xor(pm, 32));
        float alpha = 1.0f;
        float mb = mrun[g];
        if (!__all(pm - mrun[g] <= 8.0f)) {          // rescale path
          const float mnew = fmaxf(mrun[g], pm);
          alpha = __expf(mrun[g] - mnew);
          mrun[g] = mnew;
          mb = mnew;
          float al[4];
#pragma unroll
          for (int r = 0; r < 4; ++r) al[r] = __shfl(alpha, l4 * 4 + r);
#pragma unroll
          for (int fd = 0; fd < 16; ++fd)
#pragma unroll
            for (int r = 0; r < 4; ++r) o_acc[g][fd][r] *= al[r];
        }
        float ls = 0.f;
#pragma unroll
        for (int fk = 0; fk < 2; ++fk)
#pragma unroll
          for (int r = 0; r < 4; ++r) {
            e[fk][r] = __expf(e[fk][r] - mb);        // bounded by e^8
            ls += e[fk][r];
          }
        ls += __shfl_xor(ls, 16);
        ls += __shfl_xor(ls, 32);
        lrun[g] = lrun[g] * alpha + ls;

        // pack + redistribute -> lane holds P[q=l15][k = l4*8..+7]
        const int d0 = pkf16(e[0][0], e[0][1]);
        const int d1 = pkf16(e[0][2], e[0][3]);
        const int d2 = pkf16(e[1][0], e[1][1]);
        const int d3 = pkf16(e[1][2], e[1][3]);
        const int src0 = l15 + ((l4 & 1) << 5);
        const int src1 = src0 + 16;
        const bool lowk = (l4 < 2);
        const int s00 = __shfl(d0, src0);
        const int s10 = __shfl(d1, src0);
        const int s20 = __shfl(d2, src0);
        const int s30 = __shfl(d3, src0);
        const int s01 = __shfl(d0, src1);
        const int s11 = __shfl(d1, src1);
        const int s21 = __shfl(d2, src1);
        const int s31 = __shfl(d3, src1);
        i32x4 pw = { lowk ? s00 : s20, lowk ? s10 : s30,
                     lowk ? s01 : s21, lowk ? s11 : s31 };
        pa[g] = __builtin_bit_cast(h8, pw);
      }

      // ---- PV: each V fragment feeds both g ----
      __builtin_amdgcn_s_setprio(1);
#pragma unroll
      for (int fd = 0; fd < 16; ++fd) {
        o_acc[0][fd] = mfma16(pa[0], vf[fd], o_acc[0][fd]);
        o_acc[1][fd] = mfma16(pa[1], vf[fd], o_acc[1][fd]);
      }
      __builtin_amdgcn_s_setprio(0);
    }
    __syncthreads();   // buf[p] consumed; stage(kt+1) fully landed
  }

  // ---- epilogue: /l, store f16 to [b][s][h*256] ----
#pragma unroll
  for (int g = 0; g < 2; ++g) {
    const float inv = 1.0f / lrun[g];
#pragma unroll
    for (int r = 0; r < 4; ++r) {
      const float linv = __shfl(inv, l4 * 4 + r);
      const int srow = q0 + w * 32 + g * 16 + l4 * 4 + r;
      _Float16* Op = Ah + (size_t)(b * SEQ + srow) * (NH * DH) + h * DH + l15;
#pragma unroll
      for (int fd = 0; fd < 16; ++fd)
        Op[fd * 16] = (_Float16)(o_acc[g][fd][r] * linv);
    }
  }
}

// =====================================================================
// Launch. d_in: hidden, mask(unused), wq, wk, wv, wo, q_scale, k_scale.
// =====================================================================
extern "C" void kernel_launch(void* const* d_in, const int* in_sizes, int n_in,
                              void* d_out, int out_size, void* d_ws, size_t ws_size,
                              hipStream_t stream) {
  (void)in_sizes; (void)n_in; (void)out_size; (void)ws_size;
  const float* hidden  = (const float*)d_in[0];
  const float* wq      = (const float*)d_in[2];
  const float* wk      = (const float*)d_in[3];
  const float* wv      = (const float*)d_in[4];
  const float* wo      = (const float*)d_in[5];
  const float* q_scale = (const float*)d_in[6];
  const float* k_scale = (const float*)d_in[7];
  float* out = (float*)d_out;

  uint8_t* ws = (uint8_t*)d_ws;
  _Float16* hid_h = (_Float16*)ws;  ws += (size_t)MR * HID * 2;        // 16.78MB
  _Float16* Wt    = (_Float16*)ws;  ws += (size_t)3072 * HID * 2;      // 12.58MB (QKV^T; reused for wo^T)
  float*    QKVp  = (float*)ws;     ws += (size_t)MR * 3072 * 4;       // 50.33MB (reused as Ah)
  _Float16* Qh    = (_Float16*)ws;  ws += (size_t)MR * HID * 2;        // 16.78MB
  _Float16* Kh    = (_Float16*)ws;  ws += (size_t)MR * 512 * 2;        // 4.19MB
  _Float16* Vh    = (_Float16*)ws;  ws += (size_t)MR * 512 * 2;        // 4.19MB
  _Float16* Vt    = (_Float16*)ws;  ws += (size_t)MR * 512 * 2;        // 4.19MB
  float2*   tab   = (float2*)ws;    ws += (size_t)SEQ * 128 * 8;       // 2.10MB
  _Float16* Ah    = (_Float16*)QKVp;  // overlay (QKVp dead after norms)

  const dim3 blk(256);
  cvt_f16<<<dim3(8192), blk, 0, stream>>>(hidden, hid_h, MR * HID / 4);
  rope_tab<<<dim3(SEQ), dim3(128), 0, stream>>>(tab);
  wtrans<<<dim3(64, 64), blk, 0, stream>>>(wq, Wt, 2048, 2048);
  wtrans<<<dim3(16, 64), blk, 0, stream>>>(wk, Wt + (size_t)2048 * 2048, 512, 2048);
  wtrans<<<dim3(16, 64), blk, 0, stream>>>(wv, Wt + (size_t)2560 * 2048, 512, 2048);
  // fused QKV projection: [4096,2048] @ [2048,3072]
  gemm_f16<<<dim3(24, 32), blk, 0, stream>>>(hid_h, Wt, QKVp, 3072, 2048);
  // Wt is free now -> wo^T
  wtrans<<<dim3(64, 64), blk, 0, stream>>>(wo, Wt, 2048, 2048);
  norm_rope_q<<<dim3(32768), blk, 0, stream>>>(QKVp, Qh, q_scale, tab);
  norm_kv<<<dim3(16384), blk, 0, stream>>>(QKVp, Kh, Vh, k_scale, tab);
  transpose_v<<<dim3(64, 8, 4), blk, 0, stream>>>(Vh, Vt);
  attn_f16<<<dim3(32, 8, 2), dim3(128), 0, stream>>>(Qh, Kh, Vt, Ah);
  gemm_f16<<<dim3(16, 32), blk, 0, stream>>>(Ah, Wt, out, 2048, 2048);
}